// Round 11
// baseline (282.289 us; speedup 1.0000x reference)
//
#include <hip/hip_runtime.h>
#include <hip/hip_bf16.h>
#include <stdint.h>

#define BATCH   4096
#define IN_DIM  1024
#define OUT_DIM 1024
#define GRID_G  8
#define K8      16384            // spline K bytes: 2 halves (cos,sin) x 1024 i x 8 g
#define KB      1024             // base K (silu plane)
#define SPLITK  2                // kz=0: cos half, kz=1: sin half
#define TPITCH  8192             // T row bytes: 1024 i x (c1,s1) f32
#define WSCALE  256.0f           // spline weights scaled into e4m3 range

typedef __bf16 bf16x8 __attribute__((ext_vector_type(8)));
typedef __bf16 bf16x4 __attribute__((ext_vector_type(4)));
typedef float  f32x4  __attribute__((ext_vector_type(4)));
typedef int    i32x2  __attribute__((ext_vector_type(2)));
typedef int    i32x4  __attribute__((ext_vector_type(4)));
typedef int    i32x8  __attribute__((ext_vector_type(8)));

// K-PERMUTED layout (r7->r8): spline K-index = half(cos/sin) * 8192 + i*8 + (g-1).
// GEMM is K-permutation invariant; this makes A-tiles generatable from seed
// pairs (cos x, sin x) by an in-LDS Chebyshev chain, eliminating the 67 MB A8
// intermediate (134 MB of HBM round-trip), and makes the W8 fold a trivial
// coalesced stream (coeff already has g innermost).

// ---------------------------------------------------------------------------
// prep: blocks [0,1024) = features, [1024,5120) = weight fold.
// feat: silu(x)->Ab bf16; T[b][i] = (cos x, sin x) f32 pair (8 B/elem, was
//       16 B/elem A8); zeroes C (coalesced). nt on streams.
// w:    one (o,i) per thread: W8[o][p*8192+i*8+g] = ss*coeff[p][o][i][g]*WSCALE
//       (fp8, 8 B contiguous per thread -> fully coalesced); Wb = sb bf16.
// ---------------------------------------------------------------------------
__global__ __launch_bounds__(256) void prep(const float* __restrict__ x,
                                            const float* __restrict__ sb,
                                            const float* __restrict__ ss,
                                            const float* __restrict__ coeff,
                                            uint8_t* __restrict__ T,
                                            uint8_t* __restrict__ W8,
                                            __bf16* __restrict__ Ab,
                                            __bf16* __restrict__ Wb,
                                            float* __restrict__ C) {
    const int tid = threadIdx.x;

    if (blockIdx.x < 1024) {
        // ---------------- features ----------------
        const int t  = blockIdx.x * 256 + tid;       // over B*I/16
        const int b  = t >> 6;
        const int i0 = (t & 63) * 16;

        {   // zero C: block covers a contiguous 16 KB region
            float4 z = make_float4(0.f, 0.f, 0.f, 0.f);
            float4* cz = (float4*)(C + (size_t)blockIdx.x * 4096);
#pragma unroll
            for (int j = 0; j < 4; ++j) cz[j * 256 + tid] = z;
        }

        float xv[16];
        {
            const f32x4* xp = (const f32x4*)(x + (size_t)b * IN_DIM + i0);
            f32x4 q0 = __builtin_nontemporal_load(xp + 0);
            f32x4 q1 = __builtin_nontemporal_load(xp + 1);
            f32x4 q2 = __builtin_nontemporal_load(xp + 2);
            f32x4 q3 = __builtin_nontemporal_load(xp + 3);
#pragma unroll
            for (int j = 0; j < 4; ++j) {
                xv[j] = q0[j]; xv[4+j] = q1[j]; xv[8+j] = q2[j]; xv[12+j] = q3[j];
            }
        }

        float c1[16], s1[16];
        bf16x8 va, vb;
#pragma unroll
        for (int j = 0; j < 16; ++j) {
            float e  = __expf(-xv[j]);
            float sl = xv[j] * __builtin_amdgcn_rcpf(1.f + e);
            if (j < 8) va[j & 7] = (__bf16)sl; else vb[j & 7] = (__bf16)sl;
            s1[j] = __sinf(xv[j]);
            c1[j] = __cosf(xv[j]);
        }
        __builtin_nontemporal_store(va, (bf16x8*)(Ab + (size_t)b * IN_DIM + i0));
        __builtin_nontemporal_store(vb, (bf16x8*)(Ab + (size_t)b * IN_DIM + i0 + 8));

        // T: element i at byte i*8 = {c1, s1} f32
        uint8_t* tp = T + (size_t)b * TPITCH + (size_t)i0 * 8;
#pragma unroll
        for (int e2 = 0; e2 < 8; ++e2) {
            f32x4 tv; tv[0] = c1[2*e2]; tv[1] = s1[2*e2]; tv[2] = c1[2*e2+1]; tv[3] = s1[2*e2+1];
            __builtin_nontemporal_store(tv, (f32x4*)(tp + e2 * 16));
        }
    } else {
        // ---------------- weight fold: one (o,i) per thread ----------------
        const int u = (blockIdx.x - 1024) * 256 + tid;   // 0 .. 1M
        const int o = u >> 10;
        const int i = u & 1023;
        const size_t oi = (size_t)o * IN_DIM + i;

        const float s = __builtin_nontemporal_load(ss + oi) * WSCALE;
        {
            float bv = __builtin_nontemporal_load(sb + oi);
            Wb[oi] = (__bf16)bv;
        }
        uint8_t* w8 = W8 + (size_t)o * K8 + (size_t)i * 8;
#pragma unroll
        for (int p = 0; p < 2; ++p) {
            const f32x4* cp = (const f32x4*)(coeff + (((size_t)p * OUT_DIM + o) * IN_DIM + i) * GRID_G);
            f32x4 a0 = __builtin_nontemporal_load(cp + 0);
            f32x4 a1 = __builtin_nontemporal_load(cp + 1);
            int d0 = 0, d1 = 0;
            d0 = __builtin_amdgcn_cvt_pk_fp8_f32(s*a0[0], s*a0[1], d0, false);
            d0 = __builtin_amdgcn_cvt_pk_fp8_f32(s*a0[2], s*a0[3], d0, true);
            d1 = __builtin_amdgcn_cvt_pk_fp8_f32(s*a1[0], s*a1[1], d1, false);
            d1 = __builtin_amdgcn_cvt_pk_fp8_f32(s*a1[2], s*a1[3], d1, true);
            i32x2 dd; dd[0] = d0; dd[1] = d1;
            __builtin_nontemporal_store(dd, (i32x2*)(w8 + (size_t)p * 8192));
        }
    }
}

// ---------------------------------------------------------------------------
// Fused GEMM. Grid (8,32,2) = 512 blocks = 2/CU (80 KB LDS).
// Spline phase per K-tile t (i-window [t*16, t*16+16)):
//   PhaseA: A-gen (read T-tile from LDS, Chebyshev chain, pack fp8, ds_write
//           -> Abuf) ; issue T(t+1),B(t+1) ; lgkmcnt(0) ; vmcnt(8) ; barrier
//   PhaseB: 16 x mfma_scale_16x16x128 from Abuf+Bbuf ; vmcnt(4) ; barrier
// Counted vmcnt keeps 8 loads in flight across barriers (T4).
// r10 fix: NO arrays of LDS pointers (clang promotes the array initializer to
// a constant global -> invalid addrspacecast static initializer on gfx950).
// Buffer selection is by runtime ternary on scalar pointers instead.
// Base bf16 phase + epilogue: r7 scheme.
// ---------------------------------------------------------------------------
__global__ __launch_bounds__(256, 2) void gemm_all(const uint8_t* __restrict__ Tg_,
                                                   const uint8_t* __restrict__ W8,
                                                   const uint8_t* __restrict__ Ab,
                                                   const uint8_t* __restrict__ Wb,
                                                   float* __restrict__ C) {
    __shared__ __align__(16) uint8_t pool[81920];
    uint8_t* Abuf  = pool;                       // 16 KB
    uint8_t* Bb0   = pool + 16384;               // 16 KB
    uint8_t* Bb1   = pool + 32768;               // 16 KB
    uint8_t* Tb0   = pool + 49152;               // 16 KB
    uint8_t* Tb1   = pool + 65536;               // 16 KB

    const int tid = threadIdx.x;
    const int w   = tid >> 6;
    const int l   = tid & 63;
    const int flat = blockIdx.y * 8 + blockIdx.x;
    const int xcd  = flat & 7;
    const int idx  = flat >> 3;
    const int bn   = (xcd & 1) * 4 + (idx & 3);   // N/128 = 8
    const int bm   = (xcd >> 1) * 8 + (idx >> 2); // M/128 = 32
    const int kz  = blockIdx.z;                   // 0 = cos half, 1 = sin half
    const int wm  = w & 1;
    const int wn  = w >> 1;

    f32x4 acc[4][4] = {};

    const int srow   = l >> 3;
    const int schunk = ((l & 7) ^ srow) * 16;     // swizzled 16B source chunk
    const int lm = l & 15;
    const int q  = l >> 4;
    const int c0 = (q * 2) << 4, c1 = (q * 2 + 1) << 4;

    // ---------------- spline phase: 64 K-tiles, fused A-gen ----------------
    {
        const uint8_t* Tg = Tg_ + (size_t)(bm * 128 + w * 32 + srow) * TPITCH + schunk;
        const uint8_t* Bg = W8 + (size_t)(bn * 128 + w * 32 + srow) * K8 + kz * 8192 + schunk;

        auto stageT = [&](uint8_t* dst) {         // 4 vmem ops/wave
#pragma unroll
            for (int j = 0; j < 4; ++j)
                __builtin_amdgcn_global_load_lds(
                    (const uint32_t*)(Tg + (size_t)(j * 8) * TPITCH),
                    (uint32_t*)(dst + (w * 32 + j * 8) * 128), 16, 0, 0);
            Tg += 128;
        };
        auto stageB = [&](uint8_t* dst) {         // 4 vmem ops/wave
#pragma unroll
            for (int j = 0; j < 4; ++j)
                __builtin_amdgcn_global_load_lds(
                    (const uint32_t*)(Bg + (size_t)(j * 8) * K8),
                    (uint32_t*)(dst + (w * 32 + j * 8) * 128), 16, 0, 0);
            Bg += 128;
        };

        // A-gen: thread (r = tid>>1, i8 = tid&1) -> 8 elements, 64 B of A-row
        const int r   = tid >> 1;
        const int i8  = tid & 1;
        const int key = r & 7;
        auto agen = [&](const uint8_t* tsrc) {
            const uint8_t* trow = tsrc + r * 128;
            uint8_t*       arow = Abuf + r * 128;
#pragma unroll
            for (int c = 0; c < 4; ++c) {
                const int ch = ((i8 * 4 + c) ^ key) << 4;
                f32x4 tv = *(const f32x4*)(trow + ch);   // {c1,s1,c1',s1'}
                i32x4 wv;
#pragma unroll
                for (int e = 0; e < 2; ++e) {
                    float cc = tv[e * 2], sn = tv[e * 2 + 1];
                    float tc = cc + cc;
                    float g1, g2;
                    if (kz == 0) { g1 = cc; g2 = tc * cc - 1.0f; }
                    else         { g1 = sn; g2 = tc * sn; }
                    float g3 = tc * g2 - g1;
                    float g4 = tc * g3 - g2;
                    float g5 = tc * g4 - g3;
                    float g6 = tc * g5 - g4;
                    float g7 = tc * g6 - g5;
                    float g8 = tc * g7 - g6;
                    int d0 = 0, d1 = 0;
                    d0 = __builtin_amdgcn_cvt_pk_fp8_f32(g1, g2, d0, false);
                    d0 = __builtin_amdgcn_cvt_pk_fp8_f32(g3, g4, d0, true);
                    d1 = __builtin_amdgcn_cvt_pk_fp8_f32(g5, g6, d1, false);
                    d1 = __builtin_amdgcn_cvt_pk_fp8_f32(g7, g8, d1, true);
                    wv[e * 2] = d0; wv[e * 2 + 1] = d1;
                }
                *(i32x4*)(arow + ch) = wv;
            }
        };

        auto mfma = [&](const uint8_t* bsrc) {
            i32x8 bf[4];
#pragma unroll
            for (int j = 0; j < 4; ++j) {
                const int row = wn * 64 + j * 16 + lm;
                const int sw  = (row & 7) << 4;
                const uint8_t* rp = bsrc + row * 128;
                i32x4 lo = *(const i32x4*)(rp + (c0 ^ sw));
                i32x4 hi = *(const i32x4*)(rp + (c1 ^ sw));
                bf[j] = __builtin_shufflevector(lo, hi, 0, 1, 2, 3, 4, 5, 6, 7);
            }
#pragma unroll
            for (int i = 0; i < 4; ++i) {
                const int row = wm * 64 + i * 16 + lm;
                const int sw  = (row & 7) << 4;
                const uint8_t* rp = Abuf + row * 128;
                i32x4 lo = *(const i32x4*)(rp + (c0 ^ sw));
                i32x4 hi = *(const i32x4*)(rp + (c1 ^ sw));
                i32x8 af = __builtin_shufflevector(lo, hi, 0, 1, 2, 3, 4, 5, 6, 7);
#pragma unroll
                for (int j = 0; j < 4; ++j)
                    acc[i][j] = __builtin_amdgcn_mfma_scale_f32_16x16x128_f8f6f4(
                        af, bf[j], acc[i][j], 0, 0, 0, 0x7f7f7f7f, 0, 0x7f7f7f7f);
            }
        };

        stageT(Tb0); stageB(Bb0);
        asm volatile("s_waitcnt vmcnt(0)" ::: "memory");
        __builtin_amdgcn_sched_barrier(0);
        __builtin_amdgcn_s_barrier();

        for (int t = 0; t < 64; ++t) {
            const int par = t & 1;
            // PhaseA: produce A(t), prefetch (t+1)
            agen(par ? Tb1 : Tb0);
            if (t < 63) { stageT(par ? Tb0 : Tb1); stageB(par ? Bb0 : Bb1); }
            asm volatile("s_waitcnt lgkmcnt(0)" ::: "memory");
            __builtin_amdgcn_sched_barrier(0);
            if (t < 63) { asm volatile("s_waitcnt vmcnt(8)" ::: "memory"); }   // B(t) landed
            else        { asm volatile("s_waitcnt vmcnt(0)" ::: "memory"); }
            __builtin_amdgcn_sched_barrier(0);
            __builtin_amdgcn_s_barrier();
            // PhaseB: consume
            mfma(par ? Bb1 : Bb0);
            if (t < 63) {
                asm volatile("s_waitcnt vmcnt(4)" ::: "memory");               // T(t+1) landed
                __builtin_amdgcn_sched_barrier(0);
                __builtin_amdgcn_s_barrier();
            }
        }
    }

    // undo WSCALE on the fp8 spline weights
#pragma unroll
    for (int i = 0; i < 4; ++i)
#pragma unroll
        for (int j = 0; j < 4; ++j)
            acc[i][j] *= (1.0f / WSCALE);

    __syncthreads();                              // phase change: full drain once

    // ---------------- base bf16 phase: K-slice kz (8 tiles, r7 scheme) -----
    {
        uint8_t* A0 = pool;
        uint8_t* A1 = pool + 16384;
        uint8_t* B0 = pool + 32768;
        uint8_t* B1 = pool + 49152;
        const uint8_t* Ag = Ab + (size_t)(bm * 128 + w * 32 + srow) * (KB * 2) + kz * (KB * 2 / SPLITK) + schunk;
        const uint8_t* Bg = Wb + (size_t)(bn * 128 + w * 32 + srow) * (KB * 2) + kz * (KB * 2 / SPLITK) + schunk;

        auto stage = [&](uint8_t* Ad, uint8_t* Bd) {   // 8 vmem ops/wave
#pragma unroll
            for (int j = 0; j < 4; ++j) {
                __builtin_amdgcn_global_load_lds(
                    (const uint32_t*)(Ag + (size_t)(j * 8) * (KB * 2)),
                    (uint32_t*)(Ad + (w * 32 + j * 8) * 128), 16, 0, 0);
                __builtin_amdgcn_global_load_lds(
                    (const uint32_t*)(Bg + (size_t)(j * 8) * (KB * 2)),
                    (uint32_t*)(Bd + (w * 32 + j * 8) * 128), 16, 0, 0);
            }
            Ag += 128; Bg += 128;
        };
        auto compute = [&](const uint8_t* Asrc, const uint8_t* Bsrc) {
#pragma unroll
            for (int h = 0; h < 2; ++h) {
                bf16x8 af[4], bfr[4];
#pragma unroll
                for (int i = 0; i < 4; ++i) {
                    const int row = wm * 64 + i * 16 + lm;
                    af[i] = *(const bf16x8*)(Asrc + row * 128 + ((((h * 4 + q) ^ (row & 7))) << 4));
                }
#pragma unroll
                for (int j = 0; j < 4; ++j) {
                    const int row = wn * 64 + j * 16 + lm;
                    bfr[j] = *(const bf16x8*)(Bsrc + row * 128 + ((((h * 4 + q) ^ (row & 7))) << 4));
                }
#pragma unroll
                for (int i = 0; i < 4; ++i)
#pragma unroll
                    for (int j = 0; j < 4; ++j)
                        acc[i][j] = __builtin_amdgcn_mfma_f32_16x16x32_bf16(af[i], bfr[j], acc[i][j], 0, 0, 0);
            }
        };

        stage(A0, B0);
        stage(A1, B1);
        const int NT = (KB * 2 / SPLITK) / 128;   // 8
        for (int t = 0; t < NT; ++t) {
            const int par = t & 1;
            if (t < NT - 1) { asm volatile("s_waitcnt vmcnt(8)" ::: "memory"); }
            else            { asm volatile("s_waitcnt vmcnt(0)" ::: "memory"); }
            __builtin_amdgcn_sched_barrier(0);
            __builtin_amdgcn_s_barrier();
            compute(par ? A1 : A0, par ? B1 : B0);
            __builtin_amdgcn_s_barrier();
            if (t < NT - 2) stage(par ? A1 : A0, par ? B1 : B0);
        }
    }

    // epilogue: C/D layout col = lane&15, row = (lane>>4)*4 + reg
    const int row0 = bm * 128 + wm * 64 + q * 4;
    const int col0 = bn * 128 + wn * 64 + lm;
#pragma unroll
    for (int i = 0; i < 4; ++i)
#pragma unroll
        for (int j = 0; j < 4; ++j)
#pragma unroll
            for (int r = 0; r < 4; ++r)
                unsafeAtomicAdd(&C[(size_t)(row0 + i * 16 + r) * OUT_DIM + col0 + j * 16],
                                acc[i][j][r]);
}

// ---------------------------------------------------------------------------
extern "C" void kernel_launch(void* const* d_in, const int* in_sizes, int n_in,
                              void* d_out, int out_size, void* d_ws, size_t ws_size,
                              hipStream_t stream) {
    const float* x     = (const float*)d_in[0];   // (B, I)
    const float* sb    = (const float*)d_in[1];   // (O, I)
    const float* ss    = (const float*)d_in[2];   // (O, I)
    const float* coeff = (const float*)d_in[3];   // (2, O, I, G)
    float* out = (float*)d_out;                   // (B, O)

    uint8_t* T  = (uint8_t*)d_ws;                          // 4096*8192  = 33.6 MB
    uint8_t* W8 = T + (size_t)BATCH * TPITCH;              // 1024*16384 = 16.8 MB
    __bf16*  Ab = (__bf16*)(W8 + (size_t)OUT_DIM * K8);    // 4096*1024 bf16 = 8.4 MB
    __bf16*  Wb = Ab + (size_t)BATCH * KB;                 // 1024*1024 bf16 = 2.1 MB

    hipLaunchKernelGGL(prep, dim3(1024 + 4096), dim3(256), 0, stream,
                       x, sb, ss, coeff, T, W8, Ab, Wb, out);
    hipLaunchKernelGGL(gemm_all, dim3(OUT_DIM / 128, BATCH / 128, SPLITK), dim3(256), 0, stream,
                       T, W8, (const uint8_t*)Ab, (const uint8_t*)Wb, out);
}